// Round 4
// baseline (96.553 us; speedup 1.0000x reference)
//
#include <hip/hip_runtime.h>
#include <hip/hip_bf16.h>
#include <math.h>

typedef __attribute__((ext_vector_type(8))) short short8;
typedef __attribute__((ext_vector_type(4))) float floatx4;

#define N 4096
#define D 128
#define SPLITS 16
#define MARGIN 0.3f

#define GLOBAL_LOAD_LDS16(g, l) \
    __builtin_amdgcn_global_load_lds((const __attribute__((address_space(1))) void*)(g), \
                                     (__attribute__((address_space(3))) void*)(l), 16, 0, 0)

// ---------------- prep: fp32 -> bf16, exact fp32 row squared norms ---------
__global__ __launch_bounds__(256) void prep_kernel(
    const float* __restrict__ m1, const float* __restrict__ m2,
    __hip_bfloat16* __restrict__ b1, __hip_bfloat16* __restrict__ b2,
    float* __restrict__ n1, float* __restrict__ n2,
    float* __restrict__ out)
{
    if (blockIdx.x == 0 && threadIdx.x == 0) { out[0] = 0.f; out[1] = 0.f; }

    int wv   = blockIdx.x * 4 + (threadIdx.x >> 6);   // 0..4095 (2 rows each)
    int lane = threadIdx.x & 63;
    int half = lane >> 5;
    int l32  = lane & 31;

    int g = wv * 2 + half;                            // global row 0..8191
    const float* src; __hip_bfloat16* dst; float* nd; int row;
    if (g < N) { src = m1; dst = b1; nd = n1; row = g; }
    else       { src = m2; dst = b2; nd = n2; row = g - N; }

    float4 v = *(const float4*)(src + row * D + l32 * 4);
    float s = v.x * v.x + v.y * v.y + v.z * v.z + v.w * v.w;

    __hip_bfloat16 h0 = __float2bfloat16(v.x), h1 = __float2bfloat16(v.y);
    __hip_bfloat16 h2 = __float2bfloat16(v.z), h3 = __float2bfloat16(v.w);
    short4 pk;
    pk.x = *(short*)&h0; pk.y = *(short*)&h1; pk.z = *(short*)&h2; pk.w = *(short*)&h3;
    *(short4*)((short*)dst + row * D + l32 * 4) = pk;

#pragma unroll
    for (int off = 16; off > 0; off >>= 1) s += __shfl_xor(s, off, 64);
    if (l32 == 0) nd[row] = s;
}

// ---------------- main: LDS-staged fused distance + hardest mining ----------
// Double-buffered LDS B-tiles (32 cols x 128 k bf16 = 8 KB each), staged with
// global_load_lds width=16, shared by the 4 waves. Each wave owns 64 rows
// (4 A-tiles pinned in registers) so each B ds_read feeds 4 MFMAs.
// LDS XOR-swizzle: B[col][chunk j] at slot (j ^ (col&15)) -> ds_read_b128
// conflict-free. Mining on (nB - 2*dot); row norm nA added post-reduction.
__global__ __launch_bounds__(256, 2) void pair_kernel(
    const __hip_bfloat16* __restrict__ b1, const __hip_bfloat16* __restrict__ b2,
    const float* __restrict__ n1, const float* __restrict__ n2,
    const int* __restrict__ tgt,
    float* __restrict__ ap_out, float* __restrict__ an_out)
{
    const int pair   = blockIdx.z;
    const int split  = blockIdx.y;
    const int rowBlk = blockIdx.x;

    const __hip_bfloat16* A; const __hip_bfloat16* B;
    const float* nA; const float* nB;
    if (pair == 0)      { A = b1; B = b1; nA = n1; nB = n1; }
    else if (pair == 1) { A = b2; B = b2; nA = n2; nB = n2; }
    else if (pair == 2) { A = b1; B = b2; nA = n1; nB = n2; }
    else                { A = b2; B = b1; nA = n2; nB = n1; }

    __shared__ char ldsbuf[16384];                     // 2 x 8 KB

    const int tid  = threadIdx.x;
    const int wave = tid >> 6;
    const int lane = tid & 63;
    const int l16  = lane & 15;
    const int quad = lane >> 4;

    const int rowBase = rowBlk * 256 + wave * 64;      // 64 rows per wave

    // A fragments pinned: lane holds A[row=rowBase+t*16+l16][k=c*32+quad*8..+7]
    short8 afrag[4][4];
#pragma unroll
    for (int t = 0; t < 4; ++t)
#pragma unroll
        for (int c = 0; c < 4; ++c)
            afrag[t][c] = *(const short8*)((const short*)A +
                              (rowBase + t * 16 + l16) * D + c * 32 + quad * 8);

    // per-lane output rows (C/D layout: col=lane&15, row=quad*4+reg)
    float nAr[4][4]; int tAr[4][4];
#pragma unroll
    for (int t = 0; t < 4; ++t)
#pragma unroll
        for (int r = 0; r < 4; ++r) {
            int row = rowBase + t * 16 + quad * 4 + r;
            nAr[t][r] = nA[row];
            tAr[t][r] = tgt[row];
        }

    float apv[4][4], anv[4][4];
#pragma unroll
    for (int t = 0; t < 4; ++t)
#pragma unroll
        for (int r = 0; r < 4; ++r) { apv[t][r] = -INFINITY; anv[t][r] = INFINITY; }

    // staging geometry: round r (0,1): o = r*4096 + wave*1024 + lane*16
    // col=o>>8, slot=(o>>4)&15, source chunk j = slot ^ (col&15)
    int srcRel[2], dstRel[2];
#pragma unroll
    for (int r = 0; r < 2; ++r) {
        int o    = r * 4096 + wave * 1024 + lane * 16;
        int col  = o >> 8;
        int slot = (o >> 4) & 15;
        int j    = slot ^ (col & 15);
        srcRel[r] = col * 256 + j * 16;
        dstRel[r] = o;
    }
    // ds_read offsets: chunk (c*4+quad) of col l16 -> slot ^ l16
    int roff[4];
#pragma unroll
    for (int c = 0; c < 4; ++c)
        roff[c] = l16 * 256 + (((c * 4 + quad) ^ l16) << 4);

    const int colBase = split * (N / SPLITS);          // 256-col split
    const int NT = (N / SPLITS) / 32;                  // 8 iters of 32 cols
    const char* Bbytes = (const char*)B;

    // prologue: stage tile 0 into buf 0
#pragma unroll
    for (int r = 0; r < 2; ++r)
        GLOBAL_LOAD_LDS16(Bbytes + (size_t)colBase * 256 + srcRel[r],
                          ldsbuf + dstRel[r]);
    __syncthreads();

    for (int it = 0; it < NT; it += 2) {
#pragma unroll
        for (int h = 0; h < 2; ++h) {
            const int i = it + h;                      // buffer h (compile-time)
            if (i + 1 < NT) {                          // stage next into buf h^1
                const char* src = Bbytes + (size_t)(colBase + (i + 1) * 32) * 256;
#pragma unroll
                for (int r = 0; r < 2; ++r)
                    GLOBAL_LOAD_LDS16(src + srcRel[r],
                                      ldsbuf + ((h ^ 1) * 8192) + dstRel[r]);
            }
#pragma unroll
            for (int ct2 = 0; ct2 < 2; ++ct2) {
                int col = colBase + i * 32 + ct2 * 16 + l16;
                float nBc = nB[col];
                int   tBc = tgt[col];
                short8 bf[4];
#pragma unroll
                for (int c = 0; c < 4; ++c)
                    bf[c] = *(const short8*)(ldsbuf + h * 8192 + ct2 * 4096 + roff[c]);
#pragma unroll
                for (int t = 0; t < 4; ++t) {
                    floatx4 acc = {0.f, 0.f, 0.f, 0.f};
#pragma unroll
                    for (int c = 0; c < 4; ++c)
                        acc = __builtin_amdgcn_mfma_f32_16x16x32_bf16(afrag[t][c], bf[c], acc, 0, 0, 0);
#pragma unroll
                    for (int r = 0; r < 4; ++r) {
                        float d2 = fmaf(acc[r], -2.f, nBc);   // nA deferred
                        bool same = (tAr[t][r] == tBc);
                        apv[t][r] = fmaxf(apv[t][r], same ? d2 : -INFINITY);
                        anv[t][r] = fminf(anv[t][r], same ? INFINITY : d2);
                    }
                }
            }
            __syncthreads();   // next buf staged + all waves done with buf h
        }
    }

    // reduce across the 16 column-lanes; add deferred row norm
#pragma unroll
    for (int t = 0; t < 4; ++t)
#pragma unroll
        for (int r = 0; r < 4; ++r) {
            float ap = apv[t][r], an = anv[t][r];
#pragma unroll
            for (int off = 1; off < 16; off <<= 1) {
                ap = fmaxf(ap, __shfl_xor(ap, off, 16));
                an = fminf(an, __shfl_xor(an, off, 16));
            }
            if (l16 == 0) {
                int row = rowBase + t * 16 + quad * 4 + r;
                int idx = (pair * SPLITS + split) * N + row;
                ap_out[idx] = ap + nAr[t][r];
                an_out[idx] = an + nAr[t][r];
            }
        }
}

// ---------------- finalize: merge splits, sqrt, loss + precision ------------
__global__ __launch_bounds__(256) void finalize_kernel(
    const float* __restrict__ ap, const float* __restrict__ an,
    float* __restrict__ out)
{
    const int idx = blockIdx.x * 256 + threadIdx.x;     // 0..24575
    const int list = idx >> 12;
    const int r = idx & (N - 1);
    const int pp = (list < 4) ? list : (list - 2);      // ap pairs: 0,1,2,3,2,3
    const int np = (list < 4) ? list : (list - 4);      // an pairs: 0,1,2,3,0,1

    float apv = -INFINITY, anv = INFINITY;
#pragma unroll
    for (int s = 0; s < SPLITS; ++s) {
        apv = fmaxf(apv, ap[(pp * SPLITS + s) * N + r]);
        anv = fminf(anv, an[(np * SPLITS + s) * N + r]);
    }
    float apd = sqrtf(fmaxf(apv, 1e-12f));
    float and_ = sqrtf(fmaxf(anv, 1e-12f));
    float lsum = fmaxf(apd - and_ + MARGIN, 0.f);
    float psum = (and_ > apd) ? 1.f : 0.f;

#pragma unroll
    for (int off = 32; off > 0; off >>= 1) {
        lsum += __shfl_xor(lsum, off, 64);
        psum += __shfl_xor(psum, off, 64);
    }
    __shared__ float sl[4], sp[4];
    int w = threadIdx.x >> 6;
    if ((threadIdx.x & 63) == 0) { sl[w] = lsum; sp[w] = psum; }
    __syncthreads();
    if (threadIdx.x == 0) {
        float L = sl[0] + sl[1] + sl[2] + sl[3];
        float P = sp[0] + sp[1] + sp[2] + sp[3];
        const float inv = 1.f / (6.f * N);
        atomicAdd(&out[0], L * inv);
        atomicAdd(&out[1], P * inv);
    }
}

extern "C" void kernel_launch(void* const* d_in, const int* in_sizes, int n_in,
                              void* d_out, int out_size, void* d_ws, size_t ws_size,
                              hipStream_t stream)
{
    const float* m1 = (const float*)d_in[0];
    const float* m2 = (const float*)d_in[1];
    const int* tgt  = (const int*)d_in[2];
    float* out = (float*)d_out;

    char* ws = (char*)d_ws;
    __hip_bfloat16* b1 = (__hip_bfloat16*)ws;                       // 1 MB
    __hip_bfloat16* b2 = (__hip_bfloat16*)(ws + 1048576);           // 1 MB
    float* n1 = (float*)(ws + 2097152);                             // 16 KB
    float* n2 = (float*)(ws + 2097152 + 16384);                     // 16 KB
    float* ap = (float*)(ws + 2129920);                             // 1 MB (4*16*4096*4B)
    float* an = (float*)(ws + 2129920 + 1048576);                   // 1 MB

    prep_kernel<<<1024, 256, 0, stream>>>(m1, m2, b1, b2, n1, n2, out);
    pair_kernel<<<dim3(16, SPLITS, 4), 256, 0, stream>>>(b1, b2, n1, n2, tgt, ap, an);
    finalize_kernel<<<96, 256, 0, stream>>>(ap, an, out);
}

// Round 5
// 90.785 us; speedup vs baseline: 1.0635x; 1.0635x over previous
//
#include <hip/hip_runtime.h>
#include <hip/hip_bf16.h>
#include <math.h>

typedef __attribute__((ext_vector_type(8))) short short8;
typedef __attribute__((ext_vector_type(4))) float floatx4;

#define N 4096
#define D 128
#define SPLITS 8
#define MARGIN 0.3f
#define BIG 2048.0f

#define GLOBAL_LOAD_LDS16(g, l) \
    __builtin_amdgcn_global_load_lds((const __attribute__((address_space(1))) void*)(g), \
                                     (__attribute__((address_space(3))) void*)(l), 16, 0, 0)

// ---------------- prep: fp32 -> bf16, exact fp32 row squared norms ---------
__global__ __launch_bounds__(256) void prep_kernel(
    const float* __restrict__ m1, const float* __restrict__ m2,
    __hip_bfloat16* __restrict__ b1, __hip_bfloat16* __restrict__ b2,
    float* __restrict__ n1, float* __restrict__ n2,
    float* __restrict__ out)
{
    if (blockIdx.x == 0 && threadIdx.x == 0) { out[0] = 0.f; out[1] = 0.f; }

    int wv   = blockIdx.x * 4 + (threadIdx.x >> 6);   // 0..4095 (2 rows each)
    int lane = threadIdx.x & 63;
    int half = lane >> 5;
    int l32  = lane & 31;

    int g = wv * 2 + half;                            // global row 0..8191
    const float* src; __hip_bfloat16* dst; float* nd; int row;
    if (g < N) { src = m1; dst = b1; nd = n1; row = g; }
    else       { src = m2; dst = b2; nd = n2; row = g - N; }

    float4 v = *(const float4*)(src + row * D + l32 * 4);
    float s = v.x * v.x + v.y * v.y + v.z * v.z + v.w * v.w;

    __hip_bfloat16 h0 = __float2bfloat16(v.x), h1 = __float2bfloat16(v.y);
    __hip_bfloat16 h2 = __float2bfloat16(v.z), h3 = __float2bfloat16(v.w);
    short4 pk;
    pk.x = *(short*)&h0; pk.y = *(short*)&h1; pk.z = *(short*)&h2; pk.w = *(short*)&h3;
    *(short4*)((short*)dst + row * D + l32 * 4) = pk;

#pragma unroll
    for (int off = 16; off > 0; off >>= 1) s += __shfl_xor(s, off, 64);
    if (l32 == 0) nd[row] = s;
}

// ---------------- main: LDS-staged fused distance + hardest mining ----------
// Double-buffered LDS B-tiles (64 cols x 128 k bf16 = 16 KB each), staged via
// global_load_lds width=16, shared by 4 waves. Wave owns 32 rows (2 A-tiles
// pinned in registers).
// Biased single-value mining: v = (nB + same*BIG) - 2*dot. Then
//   hardest-pos d2 = max(v) - BIG + nA   (positives all carry +BIG > range)
//   hardest-neg d2 = min(v) + nA         (positives can never be the min)
// Exact because BIG=2048 exceeds the entire value range (~500); fp32
// round-off at +2048 is ~2.4e-4. Per-split merge stays exact after the
// per-split -BIG (positive-free splits store ~-1600, losing every fmax).
// LDS XOR-swizzle: B[col][chunk j] at slot (j ^ (col&15)) -> ds_read_b128
// conflict-free (verified 0 conflicts in R3).
__global__ __launch_bounds__(256, 4) void pair_kernel(
    const __hip_bfloat16* __restrict__ b1, const __hip_bfloat16* __restrict__ b2,
    const float* __restrict__ n1, const float* __restrict__ n2,
    const int* __restrict__ tgt,
    float* __restrict__ ap_out, float* __restrict__ an_out)
{
    const int pair   = blockIdx.z;
    const int split  = blockIdx.y;
    const int rowBlk = blockIdx.x;

    const __hip_bfloat16* A; const __hip_bfloat16* B;
    const float* nA; const float* nB;
    if (pair == 0)      { A = b1; B = b1; nA = n1; nB = n1; }
    else if (pair == 1) { A = b2; B = b2; nA = n2; nB = n2; }
    else if (pair == 2) { A = b1; B = b2; nA = n1; nB = n2; }
    else                { A = b2; B = b1; nA = n2; nB = n1; }

    __shared__ char ldsbuf[32768];                     // 2 x 16 KB

    const int tid  = threadIdx.x;
    const int wave = tid >> 6;
    const int lane = tid & 63;
    const int l16  = lane & 15;
    const int quad = lane >> 4;

    const int rowBase = rowBlk * 128 + wave * 32;      // 32 rows per wave

    // A fragments pinned: lane holds A[row=rowBase+t*16+l16][k=c*32+quad*8..+7]
    short8 afrag[2][4];
#pragma unroll
    for (int t = 0; t < 2; ++t)
#pragma unroll
        for (int c = 0; c < 4; ++c)
            afrag[t][c] = *(const short8*)((const short*)A +
                              (rowBase + t * 16 + l16) * D + c * 32 + quad * 8);

    // per-lane output rows (C/D layout: col=lane&15, row=quad*4+reg)
    float nAr[2][4]; int tAr[2][4];
#pragma unroll
    for (int t = 0; t < 2; ++t)
#pragma unroll
        for (int r = 0; r < 4; ++r) {
            int row = rowBase + t * 16 + quad * 4 + r;
            nAr[t][r] = nA[row];
            tAr[t][r] = tgt[row];
        }

    float apv[2][4], anv[2][4];
#pragma unroll
    for (int t = 0; t < 2; ++t)
#pragma unroll
        for (int r = 0; r < 4; ++r) { apv[t][r] = -INFINITY; anv[t][r] = INFINITY; }

    // staging geometry: round r (0..3): o = r*4096 + wave*1024 + lane*16
    // col=o>>8 (0..63), slot=(o>>4)&15, source chunk j = slot ^ (col&15)
    int srcRel[4], dstRel[4];
#pragma unroll
    for (int r = 0; r < 4; ++r) {
        int o    = r * 4096 + wave * 1024 + lane * 16;
        int col  = o >> 8;
        int slot = (o >> 4) & 15;
        int j    = slot ^ (col & 15);
        srcRel[r] = col * 256 + j * 16;
        dstRel[r] = o;
    }
    // ds_read offsets: chunk (c*4+quad) of col l16 -> slot ^ l16
    int roff[4];
#pragma unroll
    for (int c = 0; c < 4; ++c)
        roff[c] = l16 * 256 + (((c * 4 + quad) ^ l16) << 4);

    const int colBase = split * (N / SPLITS);          // 512-col split
    const int NT = (N / SPLITS) / 64;                  // 8 iters of 64 cols
    const char* Bbytes = (const char*)B;

    // prologue: stage tile 0 into buf 0
#pragma unroll
    for (int r = 0; r < 4; ++r)
        GLOBAL_LOAD_LDS16(Bbytes + (size_t)colBase * 256 + srcRel[r],
                          ldsbuf + dstRel[r]);
    __syncthreads();

    for (int it = 0; it < NT; it += 2) {
#pragma unroll
        for (int h = 0; h < 2; ++h) {
            const int i = it + h;                      // buffer h (compile-time)
            if (i + 1 < NT) {                          // stage next into buf h^1
                const char* src = Bbytes + (size_t)(colBase + (i + 1) * 64) * 256;
#pragma unroll
                for (int r = 0; r < 4; ++r)
                    GLOBAL_LOAD_LDS16(src + srcRel[r],
                                      ldsbuf + ((h ^ 1) * 16384) + dstRel[r]);
            }
#pragma unroll
            for (int ct2 = 0; ct2 < 4; ++ct2) {
                int col = colBase + i * 64 + ct2 * 16 + l16;
                float nBc = nB[col];
                int   tBc = tgt[col];
                float sBias = nBc + BIG;
                short8 bf[4];
#pragma unroll
                for (int c = 0; c < 4; ++c)
                    bf[c] = *(const short8*)(ldsbuf + h * 16384 + ct2 * 4096 + roff[c]);
#pragma unroll
                for (int t = 0; t < 2; ++t) {
                    floatx4 acc = {0.f, 0.f, 0.f, 0.f};
#pragma unroll
                    for (int c = 0; c < 4; ++c)
                        acc = __builtin_amdgcn_mfma_f32_16x16x32_bf16(afrag[t][c], bf[c], acc, 0, 0, 0);
#pragma unroll
                    for (int r = 0; r < 4; ++r) {
                        float s = (tAr[t][r] == tBc) ? sBias : nBc;   // cmp+cndmask
                        float v = fmaf(acc[r], -2.f, s);              // fma
                        apv[t][r] = fmaxf(apv[t][r], v);              // max
                        anv[t][r] = fminf(anv[t][r], v);              // min
                    }
                }
            }
            __syncthreads();   // next buf staged + all waves done with buf h
        }
    }

    // reduce across the 16 column-lanes; add deferred row norm / unbias
#pragma unroll
    for (int t = 0; t < 2; ++t)
#pragma unroll
        for (int r = 0; r < 4; ++r) {
            float ap = apv[t][r], an = anv[t][r];
#pragma unroll
            for (int off = 1; off < 16; off <<= 1) {
                ap = fmaxf(ap, __shfl_xor(ap, off, 16));
                an = fminf(an, __shfl_xor(an, off, 16));
            }
            if (l16 == 0) {
                int row = rowBase + t * 16 + quad * 4 + r;
                int idx = (pair * SPLITS + split) * N + row;
                ap_out[idx] = ap + nAr[t][r] - BIG;
                an_out[idx] = an + nAr[t][r];
            }
        }
}

// ---------------- finalize: merge splits, sqrt, loss + precision ------------
__global__ __launch_bounds__(256) void finalize_kernel(
    const float* __restrict__ ap, const float* __restrict__ an,
    float* __restrict__ out)
{
    const int idx = blockIdx.x * 256 + threadIdx.x;     // 0..24575
    const int list = idx >> 12;
    const int r = idx & (N - 1);
    const int pp = (list < 4) ? list : (list - 2);      // ap pairs: 0,1,2,3,2,3
    const int np = (list < 4) ? list : (list - 4);      // an pairs: 0,1,2,3,0,1

    float apv = -INFINITY, anv = INFINITY;
#pragma unroll
    for (int s = 0; s < SPLITS; ++s) {
        apv = fmaxf(apv, ap[(pp * SPLITS + s) * N + r]);
        anv = fminf(anv, an[(np * SPLITS + s) * N + r]);
    }
    float apd = sqrtf(fmaxf(apv, 1e-12f));
    float and_ = sqrtf(fmaxf(anv, 1e-12f));
    float lsum = fmaxf(apd - and_ + MARGIN, 0.f);
    float psum = (and_ > apd) ? 1.f : 0.f;

#pragma unroll
    for (int off = 32; off > 0; off >>= 1) {
        lsum += __shfl_xor(lsum, off, 64);
        psum += __shfl_xor(psum, off, 64);
    }
    __shared__ float sl[4], sp[4];
    int w = threadIdx.x >> 6;
    if ((threadIdx.x & 63) == 0) { sl[w] = lsum; sp[w] = psum; }
    __syncthreads();
    if (threadIdx.x == 0) {
        float L = sl[0] + sl[1] + sl[2] + sl[3];
        float P = sp[0] + sp[1] + sp[2] + sp[3];
        const float inv = 1.f / (6.f * N);
        atomicAdd(&out[0], L * inv);
        atomicAdd(&out[1], P * inv);
    }
}

extern "C" void kernel_launch(void* const* d_in, const int* in_sizes, int n_in,
                              void* d_out, int out_size, void* d_ws, size_t ws_size,
                              hipStream_t stream)
{
    const float* m1 = (const float*)d_in[0];
    const float* m2 = (const float*)d_in[1];
    const int* tgt  = (const int*)d_in[2];
    float* out = (float*)d_out;

    char* ws = (char*)d_ws;
    __hip_bfloat16* b1 = (__hip_bfloat16*)ws;                       // 1 MB
    __hip_bfloat16* b2 = (__hip_bfloat16*)(ws + 1048576);           // 1 MB
    float* n1 = (float*)(ws + 2097152);                             // 16 KB
    float* n2 = (float*)(ws + 2097152 + 16384);                     // 16 KB
    float* ap = (float*)(ws + 2129920);                             // 512 KB (4*8*4096*4B)
    float* an = (float*)(ws + 2129920 + 524288);                    // 512 KB

    prep_kernel<<<1024, 256, 0, stream>>>(m1, m2, b1, b2, n1, n2, out);
    pair_kernel<<<dim3(32, SPLITS, 4), 256, 0, stream>>>(b1, b2, n1, n2, tgt, ap, an);
    finalize_kernel<<<96, 256, 0, stream>>>(ap, an, out);
}